// Round 18
// baseline (111.046 us; speedup 1.0000x reference)
//
#include <hip/hip_runtime.h>
#include <hip/hip_bf16.h>
#include <math.h>

#define T_SEQ 2048
#define C_DIM 2048
#define NH    32
#define NKV   8
#define DH    64
#define WIN   512
#define QKV_N 3072   // 2048 Q + 512 K + 512 V

typedef __bf16 bf16x8 __attribute__((ext_vector_type(8)));
typedef __bf16 bf16x4 __attribute__((ext_vector_type(4)));
typedef float  f32x4  __attribute__((ext_vector_type(4)));

#if __has_builtin(__builtin_amdgcn_exp2f)
#define EXP2(x) __builtin_amdgcn_exp2f(x)
#else
#define EXP2(x) exp2f(x)
#endif

__device__ __forceinline__ void gload_lds16(const __bf16* g, __bf16* l) {
  __builtin_amdgcn_global_load_lds(
      (const __attribute__((address_space(1))) void*)g,
      (__attribute__((address_space(3))) void*)l, 16, 0, 0);
}

// ---------------------------------------------------------------------------
// 32x32 transpose tile (256-thread form): in[R][C] f32 -> out[C][R] bf16.
// ---------------------------------------------------------------------------
__device__ __forceinline__ void tr_tile(const float* __restrict__ in,
                                        __bf16* __restrict__ out,
                                        int R, int Ccols, int tile, int tid,
                                        float (*sh)[33]) {
  int tpc = Ccols >> 5;
  int c0 = (tile % tpc) << 5;
  int r0 = (tile / tpc) << 5;
  int tx = tid & 31, ty = tid >> 5;  // 32 x 8
#pragma unroll
  for (int i = 0; i < 32; i += 8)
    sh[ty + i][tx] = in[(size_t)(r0 + ty + i) * Ccols + c0 + tx];
  __syncthreads();
#pragma unroll
  for (int i = 0; i < 32; i += 8)
    out[(size_t)(c0 + ty + i) * R + r0 + tx] = (__bf16)sh[tx][ty + i];
}

// 512-thread form (32 x 16 threads) for the attn-launch woT region.
__device__ __forceinline__ void tr_tile512(const float* __restrict__ in,
                                           __bf16* __restrict__ out,
                                           int R, int Ccols, int tile, int tid,
                                           float (*sh)[33]) {
  int tpc = Ccols >> 5;
  int c0 = (tile % tpc) << 5;
  int r0 = (tile / tpc) << 5;
  int tx = tid & 31, ty = tid >> 5;  // 32 x 16
#pragma unroll
  for (int i = 0; i < 32; i += 16)
    sh[ty + i][tx] = in[(size_t)(r0 + ty + i) * Ccols + c0 + tx];
  __syncthreads();
#pragma unroll
  for (int i = 0; i < 32; i += 16)
    out[(size_t)(c0 + ty + i) * R + r0 + tx] = (__bf16)sh[tx][ty + i];
}

// ---------------------------------------------------------------------------
// Fused prep (everything the QKV GEMM needs; woT rides in attn launch):
//   region 0: cvt x -> xb (bf16)                     4096 blocks
//   region 1: rope cos/sin table                      256 blocks
//   region 2: wq^T  -> wqkvT[0:2048]                 4096 blocks
//   region 3: wk^T  -> wqkvT[2048:2560]              1024 blocks
//   region 4: wv^T  -> wqkvT[2560:3072]              1024 blocks
// ---------------------------------------------------------------------------
__global__ __launch_bounds__(256) void prep_kernel(
    const float* __restrict__ x, const float* __restrict__ wq,
    const float* __restrict__ wk, const float* __restrict__ wv,
    __bf16* __restrict__ xb, __bf16* __restrict__ wqkvT,
    float2* __restrict__ tab) {
  __shared__ float sh[32][33];
  int bid = blockIdx.x;
  const int tid = threadIdx.x;
  if (bid < 4096) {  // cvt
    int i = bid * 256 + tid;
    float4 v = ((const float4*)x)[i];
    bf16x4 o = {(__bf16)v.x, (__bf16)v.y, (__bf16)v.z, (__bf16)v.w};
    *(bf16x4*)(xb + (size_t)i * 4) = o;
    return;
  }
  bid -= 4096;
  if (bid < 256) {  // rope table
    int i = bid * 256 + tid;
    int j = i & 31, t = i >> 5;
    float inv = powf(10000.0f, -(float)(2 * j) / 64.0f);
    float s, c;
    sincosf((float)t * inv, &s, &c);
    tab[i] = make_float2(c, s);
    return;
  }
  bid -= 256;
  if (bid < 4096) { tr_tile(wq, wqkvT, C_DIM, C_DIM, bid, tid, sh); return; }
  bid -= 4096;
  if (bid < 1024) {
    tr_tile(wk, wqkvT + (size_t)2048 * C_DIM, C_DIM, NKV * DH, bid, tid, sh);
    return;
  }
  bid -= 1024;
  tr_tile(wv, wqkvT + (size_t)2560 * C_DIM, C_DIM, NKV * DH, bid, tid, sh);
}

// ---------------------------------------------------------------------------
// bf16 MFMA GEMM (R14-proven best): C[M][N] = A[M][K] * Bt[N][K]^T
// 128x64 tile, BK=64, 512 threads = 8 waves (wave = 16 rows x 64 cols).
// Double-buffered LDS (48 KB), one barrier per K-step, XOR swizzle
// (0 bank conflicts), T1 XCD chunking (-28% FETCH).
// ROPE: fused rotary on f32 accumulators for cols < 2560; Q region also
// pre-scaled by 0.125*log2(e) for exp2-domain softmax.
// ---------------------------------------------------------------------------
template <typename OutT, bool ROPE>
__global__ __launch_bounds__(512) void gemm_bf16_kernel(
    const __bf16* __restrict__ A, const __bf16* __restrict__ Bt,
    OutT* __restrict__ C, const float2* __restrict__ rope_tab,
    int M, int N, int K, int chx, int chy) {
  __shared__ __bf16 As[2][128 * 64];  // 2 x 16 KB
  __shared__ __bf16 Bs[2][64 * 64];   // 2 x  8 KB

  const int tid = threadIdx.x;
  const int wid = tid >> 6, l = tid & 63;   // wid 0..7
  const int lm = l & 15, lh = l >> 4;

  const int hw  = blockIdx.x;
  const int xcd = hw & 7;
  const int idx = hw >> 3;
  const int bx  = (xcd & 3) * chx + idx % chx;
  const int by  = (xcd >> 2) * chy + idx / chx;
  const int brow = by * 128, bcol = bx * 64;

  const int kb_swz = (((l & 7) ^ (l >> 3)) << 3);
  const int srow   = l >> 3;

  auto stage = [&](int kbase, int bi) {
#pragma unroll
    for (int c = 0; c < 3; ++c) {
      int ci = wid + c * 8;  // 0..23
      if (ci < 16) {
        int row = ci * 8 + srow;
        gload_lds16(A + (size_t)(brow + row) * K + kbase + kb_swz,
                    &As[bi][ci * 512]);
      } else {
        int row = (ci - 16) * 8 + srow;
        gload_lds16(Bt + (size_t)(bcol + row) * K + kbase + kb_swz,
                    &Bs[bi][(ci - 16) * 512]);
      }
    }
  };

  f32x4 acc[4] = {};
  const int NT = K >> 6;

  stage(0, 0);
  __syncthreads();

  for (int t = 0; t < NT; ++t) {
    const int cur = t & 1;
    if (t + 1 < NT) stage((t + 1) << 6, cur ^ 1);

    const __bf16* as = As[cur];
    const __bf16* bs = Bs[cur];
    const int x7 = lm & 7;
    bf16x8 af[2], bfr[4][2];
#pragma unroll
    for (int u = 0; u < 2; ++u)
      af[u] = *(const bf16x8*)&as[(wid * 16 + lm) * 64 +
                                  (((u * 4 + lh) ^ x7) << 3)];
#pragma unroll
    for (int j = 0; j < 4; ++j)
#pragma unroll
      for (int u = 0; u < 2; ++u)
        bfr[j][u] = *(const bf16x8*)&bs[(j * 16 + lm) * 64 +
                                        (((u * 4 + lh) ^ x7) << 3)];
#pragma unroll
    for (int u = 0; u < 2; ++u)
#pragma unroll
      for (int j = 0; j < 4; ++j)
        acc[j] = __builtin_amdgcn_mfma_f32_16x16x32_bf16(
            af[u], bfr[j][u], acc[j], 0, 0, 0);

    __syncthreads();
  }

  if (ROPE) {
    if (bcol < 2560) {  // Q or K region (V starts at 2560)
#pragma unroll
      for (int r = 0; r < 4; ++r) {
        int t = brow + wid * 16 + lh * 4 + r;
#pragma unroll
        for (int j = 0; j < 2; ++j) {
          float2 cs = rope_tab[t * 32 + j * 16 + lm];
          float v0 = acc[j][r], v1 = acc[j + 2][r];
          acc[j][r]     = v0 * cs.x - v1 * cs.y;
          acc[j + 2][r] = v1 * cs.x + v0 * cs.y;
        }
      }
    }
    if (bcol < 2048) {  // Q region: fold softmax scale (1/8 * log2 e)
#pragma unroll
      for (int j = 0; j < 4; ++j)
#pragma unroll
        for (int r = 0; r < 4; ++r) acc[j][r] *= 0.18033688f;
    }
  }

#pragma unroll
  for (int j = 0; j < 4; ++j)
#pragma unroll
    for (int r = 0; r < 4; ++r) {
      int row = brow + wid * 16 + lh * 4 + r;
      int col = bcol + j * 16 + lm;
      C[(size_t)row * N + col] = (OutT)acc[j][r];
    }
}

// ---------------------------------------------------------------------------
// Flash-style sliding-window GQA attention, QBLK=128 (8 waves, 512 thr).
// Each K/V tile stage+barrier pair now serves 128 queries (was 64): per-
// query staging cost x0.56, occupancy 26% -> ~50% (37 KB LDS, 2 blocks/CU).
// Wave-skip guard (compute only; barriers outside -- R2-proven pattern).
// T12 swapped QK^T, exp2-domain softmax (Q pre-scaled in GEMM epilogue).
// + fused woT transpose region (blocks >= 512).
// ---------------------------------------------------------------------------
__global__ __launch_bounds__(512) void attn_mfma_kernel(
    const __bf16* __restrict__ QKV, __bf16* __restrict__ O,
    const float* __restrict__ wo, __bf16* __restrict__ woT) {
  const int tid = threadIdx.x;

  if (blockIdx.x >= 512) {  // woT transpose region
    __shared__ float sh[32][33];
    tr_tile512(wo, woT, C_DIM, C_DIM, blockIdx.x - 512, tid, sh);
    return;
  }

  __shared__ __bf16 K_lds[64][72];      // [key][d], +8 pad   (9 KB)
  __shared__ __bf16 Vt[64][72];         // [d][key], +8 pad   (9 KB)
  __shared__ __bf16 P_lds[8][16][72];   // per-wave P tile    (18 KB)

  const int l   = tid & 63;
  const int w   = tid >> 6;                 // 0..7
  const int q0  = (blockIdx.x & 15) * 128;  // q-tile fastest (L2 locality)
  const int h   = blockIdx.x >> 4;
  const int kvh = h >> 2;
  const int q0w = q0 + w * 16;
  const int lm  = l & 15;
  const int lh  = l >> 4;

  const __bf16* Qp = QKV + h * DH;
  const __bf16* Kp = QKV + 2048 + kvh * DH;
  const __bf16* Vp = QKV + 2560 + kvh * DH;

  bf16x8 aq0 = *(const bf16x8*)(Qp + (size_t)(q0w + lm) * QKV_N + lh * 8);
  bf16x8 aq1 = *(const bf16x8*)(Qp + (size_t)(q0w + lm) * QKV_N + 32 + lh * 8);

  f32x4 o_acc[4] = {};
  float m = -60.0f, lsum = 0.0f;   // log2 domain

  const int klo  = (q0 - WIN) > 0 ? (q0 - WIN) : 0;
  // K staging: 512 threads, one bf16x8 each (64 rows x 8 chunks of 8)
  const int skey = tid >> 3;        // 0..63
  const int sdp  = (tid & 7) * 8;   // 0..56
  // V staging: key = tid&63, d-group = tid>>6 (8 groups of 8)
  const int vkey = tid & 63;
  const int vd   = (tid >> 6) * 8;

  for (int k0 = klo; k0 < q0 + 128; k0 += 64) {
    __syncthreads();
    {
      const __bf16* ks = Kp + (size_t)(k0 + skey) * QKV_N + sdp;
      *(bf16x8*)&K_lds[skey][sdp] = *(const bf16x8*)ks;
      const __bf16* vs = Vp + (size_t)(k0 + vkey) * QKV_N + vd;
      bf16x8 v0 = *(const bf16x8*)vs;
      // scalar writes Vt[d][vkey]: banks (4d + vkey/2)%32 -> conflict-free
#pragma unroll
      for (int j = 0; j < 8; ++j) Vt[vd + j][vkey] = v0[j];
    }
    __syncthreads();

    // wave-skip: tile disjoint from this wave's allowed key range
    if (k0 <= q0w + 15 && k0 + 63 >= q0w - WIN) {
      // ---- S^T = K Q^T: lane (lh,lm) holds S[k0+kg*16+lh*4+r][q0w+lm] ----
      f32x4 s[4] = {};
#pragma unroll
      for (int kg = 0; kg < 4; ++kg) {
        bf16x8 kb0 = *(const bf16x8*)&K_lds[kg * 16 + lm][lh * 8];
        bf16x8 kb1 = *(const bf16x8*)&K_lds[kg * 16 + lm][32 + lh * 8];
        s[kg] = __builtin_amdgcn_mfma_f32_16x16x32_bf16(kb0, aq0, s[kg], 0, 0, 0);
        s[kg] = __builtin_amdgcn_mfma_f32_16x16x32_bf16(kb1, aq1, s[kg], 0, 0, 0);
      }

      // ---- mask (interior fast path) ----
      float sv[4][4];
      const bool full = (k0 + 63 <= q0w) && (k0 >= q0w + 15 - WIN);
      if (full) {
#pragma unroll
        for (int kg = 0; kg < 4; ++kg)
#pragma unroll
          for (int r = 0; r < 4; ++r) sv[kg][r] = s[kg][r];
      } else {
        const int qr = q0w + lm;
#pragma unroll
        for (int kg = 0; kg < 4; ++kg)
#pragma unroll
          for (int r = 0; r < 4; ++r) {
            int kc = k0 + kg * 16 + lh * 4 + r;
            sv[kg][r] = (kc <= qr && kc + WIN >= qr) ? s[kg][r] : -1e30f;
          }
      }

      // ---- in-lane row max + 2-lane-hop reduce ----
      float t01 = fmaxf(fmaxf(fmaxf(sv[0][0], sv[0][1]), fmaxf(sv[0][2], sv[0][3])),
                        fmaxf(fmaxf(sv[1][0], sv[1][1]), fmaxf(sv[1][2], sv[1][3])));
      float t23 = fmaxf(fmaxf(fmaxf(sv[2][0], sv[2][1]), fmaxf(sv[2][2], sv[2][3])),
                        fmaxf(fmaxf(sv[3][0], sv[3][1]), fmaxf(sv[3][2], sv[3][3])));
      float tmax = fmaxf(t01, t23);
      tmax = fmaxf(tmax, __shfl_xor(tmax, 16));
      tmax = fmaxf(tmax, __shfl_xor(tmax, 32));

      float mn = fmaxf(m, tmax);
      float co = EXP2(m - mn);
      m = mn;
      float ps = 0.0f;
#pragma unroll
      for (int kg = 0; kg < 4; ++kg)
#pragma unroll
        for (int r = 0; r < 4; ++r) {
          float p = EXP2(sv[kg][r] - mn);  // masked: exp2(-huge) -> 0
          sv[kg][r] = p;
          ps += p;
        }
      ps += __shfl_xor(ps, 16);
      ps += __shfl_xor(ps, 32);
      lsum = lsum * co + ps;
#pragma unroll
      for (int dc = 0; dc < 4; ++dc)
#pragma unroll
        for (int r = 0; r < 4; ++r) o_acc[dc][r] *= co;

      // ---- P -> LDS in [q][k] layout, reread as b128 fragments ----
#pragma unroll
      for (int kg = 0; kg < 4; ++kg)
#pragma unroll
        for (int r = 0; r < 4; ++r)
          P_lds[w][lm][kg * 16 + lh * 4 + r] = (__bf16)sv[kg][r];
      bf16x8 pf0 = *(const bf16x8*)&P_lds[w][lm][lh * 8];
      bf16x8 pf1 = *(const bf16x8*)&P_lds[w][lm][32 + lh * 8];

      // ---- O^T += V^T P^T: lane holds O[q0w+lm][dc*16+lh*4+r] ----
#pragma unroll
      for (int dc = 0; dc < 4; ++dc) {
        bf16x8 vb0 = *(const bf16x8*)&Vt[dc * 16 + lm][lh * 8];
        bf16x8 vb1 = *(const bf16x8*)&Vt[dc * 16 + lm][32 + lh * 8];
        o_acc[dc] = __builtin_amdgcn_mfma_f32_16x16x32_bf16(vb0, pf0, o_acc[dc], 0, 0, 0);
        o_acc[dc] = __builtin_amdgcn_mfma_f32_16x16x32_bf16(vb1, pf1, o_acc[dc], 0, 0, 0);
      }
    }
  }

  const float inv = 1.0f / lsum;
#pragma unroll
  for (int dc = 0; dc < 4; ++dc) {
    bf16x4 ov;
#pragma unroll
    for (int r = 0; r < 4; ++r) ov[r] = (__bf16)(o_acc[dc][r] * inv);
    *(bf16x4*)&O[(size_t)(q0w + lm) * C_DIM + h * DH + dc * 16 + lh * 4] = ov;
  }
}

// ---------------------------------------------------------------------------
extern "C" void kernel_launch(void* const* d_in, const int* in_sizes, int n_in,
                              void* d_out, int out_size, void* d_ws, size_t ws_size,
                              hipStream_t stream) {
  const float* x  = (const float*)d_in[0];
  const float* wq = (const float*)d_in[1];
  const float* wk = (const float*)d_in[2];
  const float* wv = (const float*)d_in[3];
  const float* wo = (const float*)d_in[4];
  float* out = (float*)d_out;

  // workspace layout (40.5 MB)
  __bf16* xb    = (__bf16*)d_ws;                       // [2048][2048] (reused as Ab)
  __bf16* wqkvT = xb + (size_t)C_DIM * C_DIM;          // [3072][2048]
  __bf16* woT   = wqkvT + (size_t)QKV_N * C_DIM;       // [2048][2048]
  __bf16* QKV   = woT + (size_t)C_DIM * C_DIM;         // [2048][3072]
  float2* tab   = (float2*)(QKV + (size_t)T_SEQ * QKV_N);  // [2048*32]
  __bf16* Ab    = xb;  // xb dead after QKV GEMM

  // prep: cvt + rope table + wq/wk/wv transposes (one launch)
  prep_kernel<<<4096 + 256 + 4096 + 1024 + 1024, 256, 0, stream>>>(
      x, wq, wk, wv, xb, wqkvT, tab);

  // fused QKV projection with RoPE epilogue (bf16 out)
  // logical grid 48 x 16; XCD chunks 12 x 8; 512 threads (R14-proven)
  gemm_bf16_kernel<__bf16, true>
      <<<768, 512, 0, stream>>>(
          xb, wqkvT, QKV, tab, T_SEQ, QKV_N, C_DIM, 12, 8);

  // attention (QBLK=128, 512 thr) + woT transpose riding along
  attn_mfma_kernel<<<512 + 4096, 512, 0, stream>>>(QKV, Ab, wo, woT);

  // output projection (fp32 out); logical grid 32 x 16; XCD chunks 8 x 8
  gemm_bf16_kernel<float, false>
      <<<512, 512, 0, stream>>>(
          Ab, woT, out, nullptr, T_SEQ, C_DIM, C_DIM, 8, 8);
}

// Round 19
// 107.607 us; speedup vs baseline: 1.0320x; 1.0320x over previous
//
#include <hip/hip_runtime.h>
#include <hip/hip_bf16.h>
#include <math.h>

#define T_SEQ 2048
#define C_DIM 2048
#define NH    32
#define NKV   8
#define DH    64
#define WIN   512
#define QKV_N 3072   // 2048 Q + 512 K + 512 V

typedef __bf16 bf16x8 __attribute__((ext_vector_type(8)));
typedef __bf16 bf16x4 __attribute__((ext_vector_type(4)));
typedef float  f32x4  __attribute__((ext_vector_type(4)));

#if __has_builtin(__builtin_amdgcn_exp2f)
#define EXP2(x) __builtin_amdgcn_exp2f(x)
#else
#define EXP2(x) exp2f(x)
#endif

__device__ __forceinline__ void gload_lds16(const __bf16* g, __bf16* l) {
  __builtin_amdgcn_global_load_lds(
      (const __attribute__((address_space(1))) void*)g,
      (__attribute__((address_space(3))) void*)l, 16, 0, 0);
}

// ---------------------------------------------------------------------------
// 32x32 transpose tile: in[R][Ccols] f32 -> out[Ccols][R] bf16. (256 thr)
// ---------------------------------------------------------------------------
__device__ __forceinline__ void tr_tile(const float* __restrict__ in,
                                        __bf16* __restrict__ out,
                                        int R, int Ccols, int tile, int tid,
                                        float (*sh)[33]) {
  int tpc = Ccols >> 5;
  int c0 = (tile % tpc) << 5;
  int r0 = (tile / tpc) << 5;
  int tx = tid & 31, ty = tid >> 5;  // 32 x 8
#pragma unroll
  for (int i = 0; i < 32; i += 8)
    sh[ty + i][tx] = in[(size_t)(r0 + ty + i) * Ccols + c0 + tx];
  __syncthreads();
#pragma unroll
  for (int i = 0; i < 32; i += 8)
    out[(size_t)(c0 + ty + i) * R + r0 + tx] = (__bf16)sh[tx][ty + i];
}

// ---------------------------------------------------------------------------
// Fused prep (everything the QKV GEMM needs; woT rides in attn launch):
//   region 0: cvt x -> xb (bf16)                     4096 blocks
//   region 1: rope cos/sin table                      256 blocks
//   region 2: wq^T  -> wqkvT[0:2048]                 4096 blocks
//   region 3: wk^T  -> wqkvT[2048:2560]              1024 blocks
//   region 4: wv^T  -> wqkvT[2560:3072]              1024 blocks
// ---------------------------------------------------------------------------
__global__ __launch_bounds__(256) void prep_kernel(
    const float* __restrict__ x, const float* __restrict__ wq,
    const float* __restrict__ wk, const float* __restrict__ wv,
    __bf16* __restrict__ xb, __bf16* __restrict__ wqkvT,
    float2* __restrict__ tab) {
  __shared__ float sh[32][33];
  int bid = blockIdx.x;
  const int tid = threadIdx.x;
  if (bid < 4096) {  // cvt
    int i = bid * 256 + tid;
    float4 v = ((const float4*)x)[i];
    bf16x4 o = {(__bf16)v.x, (__bf16)v.y, (__bf16)v.z, (__bf16)v.w};
    *(bf16x4*)(xb + (size_t)i * 4) = o;
    return;
  }
  bid -= 4096;
  if (bid < 256) {  // rope table
    int i = bid * 256 + tid;
    int j = i & 31, t = i >> 5;
    float inv = powf(10000.0f, -(float)(2 * j) / 64.0f);
    float s, c;
    sincosf((float)t * inv, &s, &c);
    tab[i] = make_float2(c, s);
    return;
  }
  bid -= 256;
  if (bid < 4096) { tr_tile(wq, wqkvT, C_DIM, C_DIM, bid, tid, sh); return; }
  bid -= 4096;
  if (bid < 1024) {
    tr_tile(wk, wqkvT + (size_t)2048 * C_DIM, C_DIM, NKV * DH, bid, tid, sh);
    return;
  }
  bid -= 1024;
  tr_tile(wv, wqkvT + (size_t)2560 * C_DIM, C_DIM, NKV * DH, bid, tid, sh);
}

// ---------------------------------------------------------------------------
// bf16 MFMA GEMM (R14-proven best): C[M][N] = A[M][K] * Bt[N][K]^T
// 128x64 tile, BK=64, 512 threads = 8 waves (wave = 16 rows x 64 cols).
// Double-buffered LDS (48 KB), one barrier per K-step, XOR swizzle
// (0 bank conflicts), T1 XCD chunking (-28% FETCH).
// ROPE: fused rotary on f32 accumulators for cols < 2560; Q region also
// pre-scaled by 0.125*log2(e) for exp2-domain softmax.
// ---------------------------------------------------------------------------
template <typename OutT, bool ROPE>
__global__ __launch_bounds__(512) void gemm_bf16_kernel(
    const __bf16* __restrict__ A, const __bf16* __restrict__ Bt,
    OutT* __restrict__ C, const float2* __restrict__ rope_tab,
    int M, int N, int K, int chx, int chy) {
  __shared__ __bf16 As[2][128 * 64];  // 2 x 16 KB
  __shared__ __bf16 Bs[2][64 * 64];   // 2 x  8 KB

  const int tid = threadIdx.x;
  const int wid = tid >> 6, l = tid & 63;   // wid 0..7
  const int lm = l & 15, lh = l >> 4;

  const int hw  = blockIdx.x;
  const int xcd = hw & 7;
  const int idx = hw >> 3;
  const int bx  = (xcd & 3) * chx + idx % chx;
  const int by  = (xcd >> 2) * chy + idx / chx;
  const int brow = by * 128, bcol = bx * 64;

  const int kb_swz = (((l & 7) ^ (l >> 3)) << 3);
  const int srow   = l >> 3;

  auto stage = [&](int kbase, int bi) {
#pragma unroll
    for (int c = 0; c < 3; ++c) {
      int ci = wid + c * 8;  // 0..23
      if (ci < 16) {
        int row = ci * 8 + srow;
        gload_lds16(A + (size_t)(brow + row) * K + kbase + kb_swz,
                    &As[bi][ci * 512]);
      } else {
        int row = (ci - 16) * 8 + srow;
        gload_lds16(Bt + (size_t)(bcol + row) * K + kbase + kb_swz,
                    &Bs[bi][(ci - 16) * 512]);
      }
    }
  };

  f32x4 acc[4] = {};
  const int NT = K >> 6;

  stage(0, 0);
  __syncthreads();

  for (int t = 0; t < NT; ++t) {
    const int cur = t & 1;
    if (t + 1 < NT) stage((t + 1) << 6, cur ^ 1);

    const __bf16* as = As[cur];
    const __bf16* bs = Bs[cur];
    const int x7 = lm & 7;
    bf16x8 af[2], bfr[4][2];
#pragma unroll
    for (int u = 0; u < 2; ++u)
      af[u] = *(const bf16x8*)&as[(wid * 16 + lm) * 64 +
                                  (((u * 4 + lh) ^ x7) << 3)];
#pragma unroll
    for (int j = 0; j < 4; ++j)
#pragma unroll
      for (int u = 0; u < 2; ++u)
        bfr[j][u] = *(const bf16x8*)&bs[(j * 16 + lm) * 64 +
                                        (((u * 4 + lh) ^ x7) << 3)];
#pragma unroll
    for (int u = 0; u < 2; ++u)
#pragma unroll
      for (int j = 0; j < 4; ++j)
        acc[j] = __builtin_amdgcn_mfma_f32_16x16x32_bf16(
            af[u], bfr[j][u], acc[j], 0, 0, 0);

    __syncthreads();
  }

  if (ROPE) {
    if (bcol < 2560) {  // Q or K region (V starts at 2560)
#pragma unroll
      for (int r = 0; r < 4; ++r) {
        int t = brow + wid * 16 + lh * 4 + r;
#pragma unroll
        for (int j = 0; j < 2; ++j) {
          float2 cs = rope_tab[t * 32 + j * 16 + lm];
          float v0 = acc[j][r], v1 = acc[j + 2][r];
          acc[j][r]     = v0 * cs.x - v1 * cs.y;
          acc[j + 2][r] = v1 * cs.x + v0 * cs.y;
        }
      }
    }
    if (bcol < 2048) {  // Q region: fold softmax scale (1/8 * log2 e)
#pragma unroll
      for (int j = 0; j < 4; ++j)
#pragma unroll
        for (int r = 0; r < 4; ++r) acc[j][r] *= 0.18033688f;
    }
  }

#pragma unroll
  for (int j = 0; j < 4; ++j)
#pragma unroll
    for (int r = 0; r < 4; ++r) {
      int row = brow + wid * 16 + lh * 4 + r;
      int col = bcol + j * 16 + lm;
      C[(size_t)row * N + col] = (OutT)acc[j][r];
    }
}

// ---------------------------------------------------------------------------
// Flash-style sliding-window GQA attention (R14-exact structure: QBLK=64,
// 4 waves, 64-key tiles -- QBLK=128 regressed 2x in R18) + T13 defer-max:
// wave-uniform __all skip of the o_acc/lsum rescale when no lane's tile-max
// exceeds m+8. Safe because m is floored at -60 (masked p = exp2(-1e30+60)
// underflows to 0; an all-masked tile leaves m at -60 -- this floor is what
// R4's broken defer-max lacked). P bounded by 2^8, fine in bf16.
// + fused woT transpose region (blocks >= 1024).
// ---------------------------------------------------------------------------
__global__ __launch_bounds__(256) void attn_mfma_kernel(
    const __bf16* __restrict__ QKV, __bf16* __restrict__ O,
    const float* __restrict__ wo, __bf16* __restrict__ woT) {
  const int tid = threadIdx.x;

  if (blockIdx.x >= 1024) {  // woT transpose region
    __shared__ float sh[32][33];
    tr_tile(wo, woT, C_DIM, C_DIM, blockIdx.x - 1024, tid, sh);
    return;
  }

  __shared__ __bf16 K_lds[64][72];      // [key][d], +8 pad
  __shared__ __bf16 Vt[64][72];         // [d][key], +8 pad
  __shared__ __bf16 P_lds[4][16][72];   // per-wave P tile [q][k]

  const int l   = tid & 63;
  const int w   = tid >> 6;
  const int q0  = (blockIdx.x & 31) * 64;   // q-tile fastest (L2 locality)
  const int h   = blockIdx.x >> 5;
  const int kvh = h >> 2;
  const int q0w = q0 + w * 16;
  const int lm  = l & 15;
  const int lh  = l >> 4;

  const __bf16* Qp = QKV + h * DH;
  const __bf16* Kp = QKV + 2048 + kvh * DH;
  const __bf16* Vp = QKV + 2560 + kvh * DH;

  bf16x8 aq0 = *(const bf16x8*)(Qp + (size_t)(q0w + lm) * QKV_N + lh * 8);
  bf16x8 aq1 = *(const bf16x8*)(Qp + (size_t)(q0w + lm) * QKV_N + 32 + lh * 8);

  f32x4 o_acc[4] = {};
  float m = -60.0f, lsum = 0.0f;   // log2 domain; m floored at -60

  const int klo  = (q0 - WIN) > 0 ? (q0 - WIN) : 0;
  const int skey = tid >> 2;         // 0..63
  const int sdp  = (tid & 3) * 16;   // 0,16,32,48

  for (int k0 = klo; k0 < q0 + 64; k0 += 64) {
    __syncthreads();
    {
      const __bf16* ks = Kp + (size_t)(k0 + skey) * QKV_N + sdp;
      *(bf16x8*)&K_lds[skey][sdp]     = *(const bf16x8*)ks;
      *(bf16x8*)&K_lds[skey][sdp + 8] = *(const bf16x8*)(ks + 8);
      const __bf16* vs = Vp + (size_t)(k0 + l) * QKV_N + w * 16;
      bf16x8 v0 = *(const bf16x8*)vs;
      bf16x8 v1 = *(const bf16x8*)(vs + 8);
#pragma unroll
      for (int j = 0; j < 8; ++j) Vt[w * 16 + j][l]     = v0[j];
#pragma unroll
      for (int j = 0; j < 8; ++j) Vt[w * 16 + 8 + j][l] = v1[j];
    }
    __syncthreads();

    // ---- S^T = K Q^T: lane (lh,lm) holds S[k0+kg*16+lh*4+r][q0w+lm] ----
    f32x4 s[4] = {};
#pragma unroll
    for (int kg = 0; kg < 4; ++kg) {
      bf16x8 kb0 = *(const bf16x8*)&K_lds[kg * 16 + lm][lh * 8];
      bf16x8 kb1 = *(const bf16x8*)&K_lds[kg * 16 + lm][32 + lh * 8];
      s[kg] = __builtin_amdgcn_mfma_f32_16x16x32_bf16(kb0, aq0, s[kg], 0, 0, 0);
      s[kg] = __builtin_amdgcn_mfma_f32_16x16x32_bf16(kb1, aq1, s[kg], 0, 0, 0);
    }

    // ---- mask (interior fast path) ----
    float sv[4][4];
    const bool full = (k0 + 63 <= q0w) && (k0 >= q0w + 15 - WIN);
    if (full) {
#pragma unroll
      for (int kg = 0; kg < 4; ++kg)
#pragma unroll
        for (int r = 0; r < 4; ++r) sv[kg][r] = s[kg][r];
    } else {
      const int qr = q0w + lm;
#pragma unroll
      for (int kg = 0; kg < 4; ++kg)
#pragma unroll
        for (int r = 0; r < 4; ++r) {
          int kc = k0 + kg * 16 + lh * 4 + r;
          sv[kg][r] = (kc <= qr && kc + WIN >= qr) ? s[kg][r] : -1e30f;
        }
    }

    // ---- in-lane row max + 2-lane-hop reduce ----
    float t01 = fmaxf(fmaxf(fmaxf(sv[0][0], sv[0][1]), fmaxf(sv[0][2], sv[0][3])),
                      fmaxf(fmaxf(sv[1][0], sv[1][1]), fmaxf(sv[1][2], sv[1][3])));
    float t23 = fmaxf(fmaxf(fmaxf(sv[2][0], sv[2][1]), fmaxf(sv[2][2], sv[2][3])),
                      fmaxf(fmaxf(sv[3][0], sv[3][1]), fmaxf(sv[3][2], sv[3][3])));
    float tmax = fmaxf(t01, t23);
    tmax = fmaxf(tmax, __shfl_xor(tmax, 16));
    tmax = fmaxf(tmax, __shfl_xor(tmax, 32));

    // ---- T13 defer-max: skip rescale when max growth <= 8 (wave-uniform) ----
    if (!__all(tmax <= m + 8.0f)) {
      float mn = fmaxf(m, tmax);
      float co = EXP2(m - mn);
      m = mn;
      lsum *= co;
#pragma unroll
      for (int dc = 0; dc < 4; ++dc)
#pragma unroll
        for (int r = 0; r < 4; ++r) o_acc[dc][r] *= co;
    }
    float ps = 0.0f;
#pragma unroll
    for (int kg = 0; kg < 4; ++kg)
#pragma unroll
      for (int r = 0; r < 4; ++r) {
        float p = EXP2(sv[kg][r] - m);  // masked: exp2(-1e30+60) -> 0
        sv[kg][r] = p;
        ps += p;
      }
    ps += __shfl_xor(ps, 16);
    ps += __shfl_xor(ps, 32);
    lsum += ps;

    // ---- P -> LDS in [q][k] layout, reread as b128 fragments ----
#pragma unroll
    for (int kg = 0; kg < 4; ++kg)
#pragma unroll
      for (int r = 0; r < 4; ++r)
        P_lds[w][lm][kg * 16 + lh * 4 + r] = (__bf16)sv[kg][r];
    bf16x8 pf0 = *(const bf16x8*)&P_lds[w][lm][lh * 8];
    bf16x8 pf1 = *(const bf16x8*)&P_lds[w][lm][32 + lh * 8];

    // ---- O^T += V^T P^T: lane holds O[q0w+lm][dc*16+lh*4+r] ----
#pragma unroll
    for (int dc = 0; dc < 4; ++dc) {
      bf16x8 vb0 = *(const bf16x8*)&Vt[dc * 16 + lm][lh * 8];
      bf16x8 vb1 = *(const bf16x8*)&Vt[dc * 16 + lm][32 + lh * 8];
      o_acc[dc] = __builtin_amdgcn_mfma_f32_16x16x32_bf16(vb0, pf0, o_acc[dc], 0, 0, 0);
      o_acc[dc] = __builtin_amdgcn_mfma_f32_16x16x32_bf16(vb1, pf1, o_acc[dc], 0, 0, 0);
    }
  }

  const float inv = 1.0f / lsum;
#pragma unroll
  for (int dc = 0; dc < 4; ++dc) {
    bf16x4 ov;
#pragma unroll
    for (int r = 0; r < 4; ++r) ov[r] = (__bf16)(o_acc[dc][r] * inv);
    *(bf16x4*)&O[(size_t)(q0w + lm) * C_DIM + h * DH + dc * 16 + lh * 4] = ov;
  }
}

// ---------------------------------------------------------------------------
extern "C" void kernel_launch(void* const* d_in, const int* in_sizes, int n_in,
                              void* d_out, int out_size, void* d_ws, size_t ws_size,
                              hipStream_t stream) {
  const float* x  = (const float*)d_in[0];
  const float* wq = (const float*)d_in[1];
  const float* wk = (const float*)d_in[2];
  const float* wv = (const float*)d_in[3];
  const float* wo = (const float*)d_in[4];
  float* out = (float*)d_out;

  // workspace layout (40.5 MB)
  __bf16* xb    = (__bf16*)d_ws;                       // [2048][2048] (reused as Ab)
  __bf16* wqkvT = xb + (size_t)C_DIM * C_DIM;          // [3072][2048]
  __bf16* woT   = wqkvT + (size_t)QKV_N * C_DIM;       // [2048][2048]
  __bf16* QKV   = woT + (size_t)C_DIM * C_DIM;         // [2048][3072]
  float2* tab   = (float2*)(QKV + (size_t)T_SEQ * QKV_N);  // [2048*32]
  __bf16* Ab    = xb;  // xb dead after QKV GEMM

  // prep: cvt + rope table + wq/wk/wv transposes (one launch)
  prep_kernel<<<4096 + 256 + 4096 + 1024 + 1024, 256, 0, stream>>>(
      x, wq, wk, wv, xb, wqkvT, tab);

  // fused QKV projection with RoPE epilogue (bf16 out)
  // logical grid 48 x 16; XCD chunks 12 x 8; 512 threads (R14-proven)
  gemm_bf16_kernel<__bf16, true>
      <<<768, 512, 0, stream>>>(
          xb, wqkvT, QKV, tab, T_SEQ, QKV_N, C_DIM, 12, 8);

  // attention (QBLK=64, 256 thr; R14-exact) + woT transpose riding along
  attn_mfma_kernel<<<1024 + 4096, 256, 0, stream>>>(QKV, Ab, wo, woT);

  // output projection (fp32 out); logical grid 32 x 16; XCD chunks 8 x 8
  gemm_bf16_kernel<float, false>
      <<<512, 512, 0, stream>>>(
          Ab, woT, out, nullptr, T_SEQ, C_DIM, C_DIM, 8, 8);
}